// Round 3
// baseline (180.667 us; speedup 1.0000x reference)
//
#include <hip/hip_runtime.h>
#include <cmath>

// CXLoss pipeline, revision 21.
// R20 profile: k_gemm9 51.1us (MfmaUtil 26%, WRITE 131.6MB = ideal), total
// 176.5us => non-gemm ~125us. Three changes:
// 1. k_gemm: Eb double-buffered + store epilogue pipelined by 1 iter ->
//    2 barriers/iter (was 3); stores+prefetch issued after sync1 overlap the
//    MFMA window instead of being vmcnt(0)-drained immediately.
// 2. k_pass1: short8 (16B) S loads, thread owns 8 consecutive q. Bit-identical
//    partials (same NP1=32 chunks, same p-order). grid 1024->256.
// 3. k_pass2: short8 S loads; gamma/beta staged in pad-10 LDS [it][lane][10]
//    (<=2-way bank conflicts), hoisted per q-window across 4 rows. fmax is
//    order-independent -> bit-identical.

#define NB 4
#define CC 256
#define HW 4096
#define NQ0 8    // gemm loop-split (CMAX partials)
#define NP1 32   // pass1 p-chunks (WSUM partials)

static constexpr float kEPS = 1e-8f;
static constexpr float kSIG = 0.1f + 1e-8f;

typedef __attribute__((ext_vector_type(8)))  short short8;
typedef __attribute__((ext_vector_type(16))) float f32x16;

// workspace layout (float units)
enum {
  OFF_MEAN = 0,                        // 256 channel means
  OFF_CMAX = 256,                      // NQ0*NB*HW colmax partials
  OFF_WSUM = OFF_CMAX + NQ0*NB*HW,     // NP1*NB*HW Wsum partials
  OFF_MAXV = OFF_WSUM + NP1*NB*HW,     // NB*HW maxv (direct)
  OFF_GB   = OFF_MAXV + NB*HW,         // gamma[NB*HW], beta[NB*HW]
  OFF_GT   = OFF_GB + 2*NB*HW,         // NB*HW*CC bf16, fragment-tiled
  OFF_GI   = OFF_GT + NB*HW*CC/2,
  OFF_S    = OFF_GI + NB*HW*CC/2,      // NB*HW*HW bf16  (134 MB)
  WS_FLOATS_FULL = OFF_S + NB*HW*HW/2
};

__device__ __forceinline__ ushort cvt_bf16(float x) {
  unsigned u = __float_as_uint(x);
  unsigned r = (u + 0x7fffu + ((u >> 16) & 1u)) >> 16;  // round-nearest-even
  return (ushort)r;
}
__device__ __forceinline__ float bf2f(ushort u) {
  return __uint_as_float((unsigned)u << 16);
}

__device__ __forceinline__ float blockSum256(float v) {
  __shared__ float sh[4];
  const int lane = threadIdx.x & 63, wv = threadIdx.x >> 6;
  #pragma unroll
  for (int o = 32; o > 0; o >>= 1) v += __shfl_down(v, o, 64);
  __syncthreads();
  if (lane == 0) sh[wv] = v;
  __syncthreads();
  return sh[0] + sh[1] + sh[2] + sh[3];
}

// K1: per-channel mean of featureT. grid=256
__global__ __launch_bounds__(256) void k_mean9(const float* __restrict__ fT,
                                               float* __restrict__ ws) {
  const int c = blockIdx.x, t = threadIdx.x;
  float s = 0.f;
  for (int n = 0; n < NB; ++n) {
    const float* p = fT + (size_t)(n*CC + c)*HW;
    #pragma unroll
    for (int k = 0; k < 16; ++k) s += p[k*256 + t];
  }
  const float tot = blockSum256(s);
  if (t == 0) ws[OFF_MEAN + c] = tot * (1.0f/16384.0f);
}

// K2: fused normalize + fragment-tiled bf16 write (verified R14 layout):
// offset_ushort(n, r32, kc) = ((n*128 + r32)*16 + kc)*512 + l*8
//   holds X[n][p = r32*32 + (l&31)][c = kc*16 + (l>>5)*8 + j], j<8.
// grid = 2 * NB * 128 = 1024 blocks.
__global__ __launch_bounds__(256) void k_prep9(const float* __restrict__ fT,
                                               const float* __restrict__ fI,
                                               float* __restrict__ ws) {
  __shared__ float stage[32][257];
  __shared__ float prt[8][32];
  __shared__ float sinv[32];
  const int t = threadIdx.x, l = t & 63;
  int bid = blockIdx.x;
  const int tensor = (bid >= 512); bid &= 511;
  const int n   = bid >> 7;
  const int r32 = bid & 127;
  const int p0  = r32 * 32;

  const float* __restrict__ src = tensor ? fI : fT;
  ushort* __restrict__ dst = (ushort*)(ws + (tensor ? OFF_GI : OFF_GT));
  const float* __restrict__ mean = ws + OFF_MEAN;

  const int pl = t & 31, cg = t >> 5;
  float acc = 0.f;
  #pragma unroll
  for (int i = 0; i < 32; ++i) {
    const int c = cg*32 + i;
    const float v = src[((size_t)(n*CC + c))*HW + p0 + pl] - mean[c];
    stage[pl][c] = v;
    acc += v*v;
  }
  prt[cg][pl] = acc;
  __syncthreads();
  if (t < 32) {
    float s = 0.f;
    #pragma unroll
    for (int g = 0; g < 8; ++g) s += prt[g][t];
    sinv[t] = 1.0f/(sqrtf(s) + kEPS);
  }
  __syncthreads();

  const int w = t >> 6, lhi = l >> 5, m = l & 31;
  const float iv = sinv[m];
  #pragma unroll
  for (int i = 0; i < 4; ++i) {
    const int kc = w*4 + i;
    const int cb = kc*16 + lhi*8;
    short8 o;
    #pragma unroll
    for (int j = 0; j < 8; ++j)
      ((ushort*)&o)[j] = cvt_bf16(stage[m][cb + j] * iv);
    *(short8*)(dst + (((size_t)(n*128 + r32)*16 + kc) << 9) + l*8) = o;
  }
}

// K3: single GEMM sweep + bf16 S store + colmax.
// 2 barriers/iter: Ab single-buffer (pf regs are the double buffer),
// Eb double-buffered, store epilogue pipelined one iteration behind.
// grid = NB*32strips*NQ0 = 1024 blocks, 4 blocks/CU. LDS 33.5KB.
__global__ __launch_bounds__(256, 4) void k_gemm9(
    const ushort* __restrict__ gA, const ushort* __restrict__ gB,
    float* __restrict__ ws)
{
  __shared__ ushort Ab[8192];        // 32-row A tile (16KB)
  __shared__ ushort Eb[2][32*136];   // epilogue buffers (2 x 8.5KB, pad 8)
  __shared__ float red2[128];

  const int t = threadIdx.x;
  const int w = t >> 6, l = t & 63;
  const int ln31 = l & 31, lhi = l >> 5;

  const int b = blockIdx.x;
  const int h = b & 7, sid = b >> 3;
  const int n = sid >> 5;
  const int col0 = (sid & 31) * 128;

  const ushort* __restrict__ gAn = gA + (size_t)(n*128 + h*16)*8192;

  // prologue: pf <- tile 0 (register prefetch is the A double buffer)
  short8 pf[4];
  #pragma unroll
  for (int i = 0; i < 4; ++i)
    pf[i] = *(const short8*)(gAn + (size_t)(i*256 + t)*8);

  // B fragments: wave w owns col-tile RB
  const int RB = (col0 >> 5) + w;
  short8 breg[16];
  #pragma unroll
  for (int kc = 0; kc < 16; ++kc)
    breg[kc] = *(const short8*)(gB +
        (((size_t)(n*128 + RB)*16 + kc) << 9) + l*8);

  ushort* __restrict__ Sn = (ushort*)(ws + OFF_S) + (size_t)n*HW*HW;

  const int ecol = w*32 + ln31;      // this lane's q column within Eb (0..127)
  const int rrow = t >> 4;           // read-back row 0..15 (+16*k)
  const int rq   = (t & 15) * 8;     // read-back q offset (ushorts)

  float runl = -3.0e38f;

  for (int iter = 0; iter < 16; ++iter) {
    __syncthreads();                 // sync0: prev MFMA reads + prev Eb reads done
    #pragma unroll
    for (int i = 0; i < 4; ++i)
      *(short8*)&Ab[(i*256 + t)*8] = pf[i];
    __syncthreads();                 // sync1: Ab staged; Eb[(iter-1)&1] visible

    // pipelined store: write out PREVIOUS iter's tile (overlaps this MFMA)
    if (iter > 0) {
      const int pb = h*512 + (iter - 1)*32;
      const ushort* __restrict__ Ep = &Eb[(iter - 1) & 1][0];
      #pragma unroll
      for (int k = 0; k < 2; ++k) {
        const int lr = rrow + 16*k;
        const short8 v = *(const short8*)&Ep[lr*136 + rq];
        *(short8*)(Sn + (size_t)(pb + lr)*HW + col0 + rq) = v;
      }
    }
    // prefetch next A tile (overlaps this MFMA; drained at next sync0)
    if (iter + 1 < 16) {
      const ushort* __restrict__ src = gAn + (size_t)(iter + 1)*8192;
      #pragma unroll
      for (int i = 0; i < 4; ++i)
        pf[i] = *(const short8*)(src + (size_t)(i*256 + t)*8);
    }

    f32x16 acc;
    #pragma unroll
    for (int e = 0; e < 16; ++e) acc[e] = 0.f;
    #pragma unroll
    for (int kc = 0; kc < 16; ++kc) {
      const short8 a0 = *(const short8*)&Ab[kc*512 + l*8];
      acc = __builtin_amdgcn_mfma_f32_32x32x16_bf16(a0, breg[kc], acc, 0, 0, 0);
    }

    // round -> colmax over ROUNDED values (bit-consistent) -> stage into Eb.
    // C/D map: col = lane&31 (q), row = (reg&3) + 8*(reg>>2) + 4*(lane>>5)
    ushort* __restrict__ Ec = &Eb[iter & 1][0];
    #pragma unroll
    for (int r = 0; r < 16; ++r) {
      const int lrow = 4*lhi + (r & 3) + 8*(r >> 2);   // 0..31
      const ushort u = cvt_bf16(acc[r]);
      Ec[lrow*136 + ecol] = u;
      runl = fmaxf(runl, bf2f(u));
    }
  }

  __syncthreads();                   // Eb[15&1] staged
  {
    const int pb = h*512 + 15*32;
    const ushort* __restrict__ Ep = &Eb[1][0];
    #pragma unroll
    for (int k = 0; k < 2; ++k) {
      const int lr = rrow + 16*k;
      const short8 v = *(const short8*)&Ep[lr*136 + rq];
      *(short8*)(Sn + (size_t)(pb + lr)*HW + col0 + rq) = v;
    }
  }

  {
    const float o = __shfl_xor(runl, 32, 64);
    runl = fmaxf(runl, o);
  }
  if (l < 32) red2[w*32 + ln31] = runl;
  __syncthreads();
  if (t < 128)
    ws[OFF_CMAX + h*(NB*HW) + n*HW + col0 + t] = red2[t];
}

// K4: pass1 — Wsum partials, short8 (16B) loads. Thread owns 8 consecutive q.
// grid = NB * 2 * 32 = 256. Bit-identical partials to R20 (same NP1=32
// chunks, same sequential p-order per chunk, same CMAX hh-order).
__global__ __launch_bounds__(256) void k_pass1(float* __restrict__ ws) {
  const int t = threadIdx.x;
  const int b = blockIdx.x;
  const int pc = b & 31, rest = b >> 5;
  const int n = rest >> 1, qh = rest & 1;
  const int q = qh*2048 + t*8;

  float aa[8], bb[8];
  {
    float cm[8];
    {
      float4 x0 = *(const float4*)&ws[OFF_CMAX + n*HW + q];
      float4 x1 = *(const float4*)&ws[OFF_CMAX + n*HW + q + 4];
      cm[0]=x0.x; cm[1]=x0.y; cm[2]=x0.z; cm[3]=x0.w;
      cm[4]=x1.x; cm[5]=x1.y; cm[6]=x1.z; cm[7]=x1.w;
    }
    #pragma unroll
    for (int hh = 1; hh < NQ0; ++hh) {
      const float4 y0 = *(const float4*)&ws[OFF_CMAX + hh*(NB*HW) + n*HW + q];
      const float4 y1 = *(const float4*)&ws[OFF_CMAX + hh*(NB*HW) + n*HW + q + 4];
      cm[0]=fmaxf(cm[0],y0.x); cm[1]=fmaxf(cm[1],y0.y);
      cm[2]=fmaxf(cm[2],y0.z); cm[3]=fmaxf(cm[3],y0.w);
      cm[4]=fmaxf(cm[4],y1.x); cm[5]=fmaxf(cm[5],y1.y);
      cm[6]=fmaxf(cm[6],y1.z); cm[7]=fmaxf(cm[7],y1.w);
    }
    #pragma unroll
    for (int j = 0; j < 8; ++j) {
      const float iv = 1.0f/(2.0f*(0.5f*(1.0f - cm[j]) + kEPS));
      bb[j] = iv / kSIG; aa[j] = (1.0f - iv) / kSIG;
    }
  }

  const ushort* __restrict__ S =
      (const ushort*)(ws + OFF_S) + (size_t)n*HW*HW + q;
  float acc[8];
  #pragma unroll
  for (int j = 0; j < 8; ++j) acc[j] = 0.f;
  const int p0 = pc*128;
  #pragma unroll 4
  for (int i = 0; i < 128; ++i) {
    const short8 u = *(const short8*)(S + (size_t)(p0 + i)*HW);
    #pragma unroll
    for (int j = 0; j < 8; ++j)
      acc[j] += __expf(fmaf(bb[j], bf2f(((const ushort*)&u)[j]), aa[j]));
  }
  float4 o0; o0.x=acc[0]; o0.y=acc[1]; o0.z=acc[2]; o0.w=acc[3];
  float4 o1; o1.x=acc[4]; o1.y=acc[5]; o1.z=acc[6]; o1.w=acc[7];
  *(float4*)&ws[OFF_WSUM + pc*(NB*HW) + n*HW + q]     = o0;
  *(float4*)&ws[OFF_WSUM + pc*(NB*HW) + n*HW + q + 4] = o1;
}

// K5: gamma/beta arrays. grid = 64 (NB*HW/256).
__global__ __launch_bounds__(256) void k_gb9(float* __restrict__ ws) {
  const int idx = blockIdx.x*256 + threadIdx.x;   // n*HW + q
  float cm = -3.0e38f;
  #pragma unroll
  for (int hh = 0; hh < NQ0; ++hh)
    cm = fmaxf(cm, ws[OFF_CMAX + hh*(NB*HW) + idx]);
  const float inv2d = 1.0f/(2.0f*(0.5f*(1.0f - cm) + kEPS));
  const float beta  = inv2d / kSIG;
  const float alpha = (1.0f - inv2d) / kSIG;
  float sw = 0.f;
  #pragma unroll
  for (int pc = 0; pc < NP1; ++pc)
    sw += ws[OFF_WSUM + pc*(NB*HW) + idx];
  ws[OFF_GB + idx]         = alpha - logf(sw + kEPS);  // gamma
  ws[OFF_GB + NB*HW + idx] = beta;
}

// K6: pass2 — maxv[n][p] = max_q (gamma_q + beta_q * s[p][q]).
// grid = NB * 256 = 1024; block owns 16 p-rows. short8 (16B) S loads.
// gamma/beta staged in pad-10 LDS [it][lane][10] (<=2-way bank conflicts),
// hoisted per q-window across the 4 rows. fmax order-independent.
__global__ __launch_bounds__(256) void k_pass2(float* __restrict__ ws) {
  __shared__ float gqp[8*640];   // 20KB: it*640 + lane*10 + j
  __shared__ float bqp[8*640];   // 20KB
  const int t = threadIdx.x, w = t >> 6, l = t & 63;
  const int b = blockIdx.x;
  const int n = b >> 8, pg = b & 255;

  const float* __restrict__ G  = ws + OFF_GB + n*HW;
  const float* __restrict__ Bq = ws + OFF_GB + NB*HW + n*HW;
  #pragma unroll
  for (int pass = 0; pass < 4; ++pass) {
    const int q = pass*1024 + t*4;
    const int a = (q >> 9)*640 + ((q >> 3) & 63)*10 + (q & 7);
    const float4 g  = *(const float4*)&G[q];
    const float4 bv = *(const float4*)&Bq[q];
    float2 w0; w0.x=g.x;  w0.y=g.y;  *(float2*)&gqp[a]   = w0;
    float2 w1; w1.x=g.z;  w1.y=g.w;  *(float2*)&gqp[a+2] = w1;
    float2 w2; w2.x=bv.x; w2.y=bv.y; *(float2*)&bqp[a]   = w2;
    float2 w3; w3.x=bv.z; w3.y=bv.w; *(float2*)&bqp[a+2] = w3;
  }
  __syncthreads();

  const ushort* __restrict__ S =
      (const ushort*)(ws + OFF_S) + (size_t)n*HW*HW;
  const int p = pg*16 + w*4;

  float m[4];
  #pragma unroll
  for (int r = 0; r < 4; ++r) m[r] = -3.0e38f;

  #pragma unroll 2
  for (int it = 0; it < 8; ++it) {
    const int abase = it*640 + l*10;
    float g[8], bb[8];
    #pragma unroll
    for (int k = 0; k < 4; ++k) {
      const float2 gv = *(const float2*)&gqp[abase + 2*k];
      const float2 bv = *(const float2*)&bqp[abase + 2*k];
      g[2*k] = gv.x;  g[2*k+1] = gv.y;
      bb[2*k] = bv.x; bb[2*k+1] = bv.y;
    }
    const int qo = it*512 + l*8;
    #pragma unroll
    for (int r = 0; r < 4; ++r) {
      const short8 u = *(const short8*)(S + (size_t)(p + r)*HW + qo);
      #pragma unroll
      for (int j = 0; j < 8; ++j)
        m[r] = fmaxf(m[r], fmaf(bb[j], bf2f(((const ushort*)&u)[j]), g[j]));
    }
  }

  #pragma unroll
  for (int r = 0; r < 4; ++r) {
    float mv = m[r];
    #pragma unroll
    for (int o = 32; o > 0; o >>= 1) mv = fmaxf(mv, __shfl_xor(mv, o, 64));
    if (l == 0) ws[OFF_MAXV + n*HW + p + r] = mv;
  }
}

// K7: final loss. one block.
__global__ __launch_bounds__(256) void k_final9(const float* __restrict__ ws,
                                                float* __restrict__ out) {
  const int t = threadIdx.x;
  float loss = 0.f;
  for (int n = 0; n < NB; ++n) {
    float s = 0.f;
    for (int k = 0; k < 16; ++k)
      s += __expf(ws[OFF_MAXV + n*HW + k*256 + t]);
    const float tot = blockSum256(s);
    loss += -logf(tot*(1.0f/4096.0f) + kEPS);
  }
  if (t == 0) out[0] = loss*0.25f;
}

extern "C" void kernel_launch(void* const* d_in, const int* in_sizes, int n_in,
                              void* d_out, int out_size, void* d_ws, size_t ws_size,
                              hipStream_t stream) {
  const float* fT = (const float*)d_in[0];
  const float* fI = (const float*)d_in[1];
  float* out = (float*)d_out;
  float* ws  = (float*)d_ws;

  const size_t need_full = (size_t)WS_FLOATS_FULL * sizeof(float);
  if (ws_size < need_full) return;  // ws measured 256 MB (R2); need ~154 MB

  const ushort* GT = (const ushort*)(ws + OFF_GT);
  const ushort* GI = (const ushort*)(ws + OFF_GI);
  k_mean9 <<<256,  256, 0, stream>>>(fT, ws);
  k_prep9 <<<1024, 256, 0, stream>>>(fT, fI, ws);
  k_gemm9 <<<1024, 256, 0, stream>>>(GT, GI, ws);   // S + colmax partials
  k_pass1 <<<256,  256, 0, stream>>>(ws);           // Wsum partials
  k_gb9   <<<64,   256, 0, stream>>>(ws);           // gamma/beta arrays
  k_pass2 <<<1024, 256, 0, stream>>>(ws);           // maxv
  k_final9<<<1,    256, 0, stream>>>(ws, out);
}